// Round 14
// baseline (646.101 us; speedup 1.0000x reference)
//
#include <hip/hip_runtime.h>

#define NPTS   16384
#define KCODES 8192
#define DDIM   256
#define HWSZ   1024
#define CHW    (DDIM * HWSZ)          // 262144
#define OUT_ELEMS 4194304
#define LOSS_OFF  OUT_ELEMS
#define IDX_OFF   (OUT_ELEMS + 1)

#define PTB    64                // points per block; 256 blocks = 1/CU
#define NTILE  64                // code tiles of 128
#define SE_OFF_B (8 * 1024 * 1024)   // 8 MB fragment images, then se[8192] f32

typedef _Float16 half_t;
typedef __attribute__((ext_vector_type(8)))  _Float16 half8;
typedef __attribute__((ext_vector_type(16))) float    v16f;

union HU { _Float16 h; unsigned short u; };

// ef layout (fragment-linear): seg = (tile*4+kc)*4+cg -> 8 KB block.
// half8 index = s*128 + h*64 + lane (s=K32-step, h=hi/lo, lane=hsel*32+col).
// Split formulas BIT-IDENTICAL to R7-R13 (proven absmax 0).
__global__ void prep_frag(const float* __restrict__ emb,
                          unsigned short* __restrict__ ef)
{
    const int tid = blockIdx.x * 256 + threadIdx.x;   // 0..262143
    const int c   = tid >> 5;                         // code
    const int k8  = tid & 31;                         // 8-k chunk
    const float4 va = *(const float4*)(emb + (size_t)c * DDIM + k8 * 8);
    const float4 vb = *(const float4*)(emb + (size_t)c * DDIM + k8 * 8 + 4);
    const float f[8] = {va.x, va.y, va.z, va.w, vb.x, vb.y, vb.z, vb.w};
    unsigned int hw[4], lw[4];
    #pragma unroll
    for (int j = 0; j < 4; ++j) {
        HU ha, hb, la, lb;
        const float E0 = f[2*j] * 64.f, E1 = f[2*j+1] * 64.f;
        const half_t h0 = (half_t)E0, h1 = (half_t)E1;
        ha.h = h0; hb.h = h1;
        la.h = (half_t)((E0 - (float)h0) * 2048.f);
        lb.h = (half_t)((E1 - (float)h1) * 2048.f);
        hw[j] = (unsigned)ha.u | ((unsigned)hb.u << 16);
        lw[j] = (unsigned)la.u | ((unsigned)lb.u << 16);
    }
    const int tile = c >> 7, r = c & 127;
    const int cg = r >> 5, col = r & 31;
    const int kc = k8 >> 3, kk = k8 & 7;
    const int s = kk >> 1, hsel = kk & 1;
    const int lane = hsel * 32 + col;
    const size_t base = ((size_t)((tile * 4 + kc) * 4 + cg)) * 4096
                      + (size_t)(s * 2) * 512 + lane * 8;
    *(uint4*)&ef[base]       = make_uint4(hw[0], hw[1], hw[2], hw[3]);
    *(uint4*)&ef[base + 512] = make_uint4(lw[0], lw[1], lw[2], lw[3]);
}

__global__ void prep_se(const float* __restrict__ emb, float* __restrict__ se)
{
    const int gw   = (blockIdx.x * 256 + threadIdx.x) >> 6;  // 0..255
    const int lane = threadIdx.x & 63;
    for (int i = 0; i < 32; ++i) {
        const int c = gw * 32 + i;
        const float4 v = *(const float4*)(emb + (size_t)c * DDIM + lane * 4);
        float ps = v.x * v.x;
        ps = fmaf(v.y, v.y, ps); ps = fmaf(v.z, v.z, ps); ps = fmaf(v.w, v.w, ps);
        float tot = ps;
        #pragma unroll
        for (int off = 1; off < 64; off <<= 1) tot += __shfl_xor(tot, off);
        if (lane == 0) se[c] = tot;
    }
}

// 4 waves/block (1/SIMD), each wave owns a cg column and computes BOTH
// 32-point halves from x-LDS -> per-CU B traffic halves to 8 MB vs R13.
// B streams global->VGPR dbuf, no barriers in the K-loop.
// dist = fl(fl(s+se) - 2m) fp32; ascending-code strict < (proven R1-R13).
// NOTE: never pass a second __launch_bounds__ arg on this toolchain (R4).
__launch_bounds__(256)
__global__ void vq_kernel(const float* __restrict__ x,
                          const unsigned short* __restrict__ ef,
                          const float* __restrict__ wse,
                          const float* __restrict__ emb,
                          float* __restrict__ out)
{
    __shared__ __align__(16) unsigned short ldsXH[PTB * 256];  // 32768 B
    __shared__ __align__(16) unsigned short ldsXL[PTB * 256];  // 32768 B
    __shared__ float  ldsS[PTB];
    __shared__ float  ldsFD[4][64];
    __shared__ int    ldsFI[4][64];
    __shared__ int    ldsI[PTB];
    __shared__ double ldsL[4];

    const int t    = threadIdx.x;
    const int lane = t & 63;
    const int w    = t >> 6;          // 0..3
    const int cg   = w;               // code-group column
    const int n0   = blockIdx.x * PTB;
    const int b    = n0 / HWSZ;
    const int hw0  = n0 % HWSZ;
    const float* xs = x + (size_t)b * CHW + hw0;   // xs[c*HWSZ + p]

    const int hsel = lane >> 5;
    const int r0   = lane & 31;                    // pg0 row
    const int r1   = r0 + 32;                      // pg1 row
    const int rs7  = r0 & 7;                       // == r1 & 7

    // ---- prologue: waves 0,1 stage x hi/lo into swizzled LDS + s[p] ----
    if (w < 2) {
        const int row = w * 32 + r0;
        const float* xp = xs + row;
        float sq = 0.f;
        #pragma unroll
        for (int xc = 0; xc < 16; ++xc) {
            const int kb = xc * 2 + hsel;
            const int ao = row * 256 + ((kb ^ (row & 7)) * 8);
            #pragma unroll
            for (int j = 0; j < 8; ++j) {
                const int c = xc * 16 + hsel * 8 + j;
                const float v = xp[(size_t)c * HWSZ];
                const half_t hh = (half_t)v;
                const half_t hl = (half_t)((v - (float)hh) * 2048.0f);
                HU u0; u0.h = hh; ldsXH[ao + j] = u0.u;
                HU u1; u1.h = hl; ldsXL[ao + j] = u1.u;
                sq = fmaf(v, v, sq);
            }
        }
        const float s_p = sq + __shfl_xor(sq, 32); // bit-identical to R13 order
        if (lane < 32) ldsS[row] = s_p;
    }
    __syncthreads();

    float s_frag[32];                              // [pgi*16+q]
    #pragma unroll
    for (int pgi = 0; pgi < 2; ++pgi)
        #pragma unroll
        for (int q = 0; q < 16; ++q) {
            const int rl = (q & 3) + 8 * (q >> 2) + 4 * hsel;
            s_frag[pgi * 16 + q] = ldsS[pgi * 32 + rl];
        }

    float best_d[32]; int best_i[32];
    #pragma unroll
    for (int q = 0; q < 32; ++q) { best_d[q] = 3.4e38f; best_i[q] = 0; }

    const int rr = cg * 32 + r0;                   // code within 128-tile
    float se_reg = 0.f;
    v16f acc_hh0, acc_hl0, acc_hh1, acc_hl1;

    const half8* EB = (const half8*)ef;
    half8 BhA[4], BlA[4], BhB[4], BlB[4];

#define LOADB(seq, BH, BL) do { \
        const half8* _bp = EB + ((size_t)((((seq) & 255) * 4 + cg)) * 512) + lane; \
        BH[0] = _bp[0];   BL[0] = _bp[64]; \
        BH[1] = _bp[128]; BL[1] = _bp[192]; \
        BH[2] = _bp[256]; BL[2] = _bp[320]; \
        BH[3] = _bp[384]; BL[3] = _bp[448]; \
    } while (0)

#define MSTEP(kc, BH, BL) do { \
        _Pragma("unroll") \
        for (int s = 0; s < 4; ++s) { \
            const int kb = ((kc) * 4 + s) * 2 + hsel; \
            const int ao = r0 * 256 + ((kb ^ rs7) * 8); \
            const half8 ah0 = *(const half8*)&ldsXH[ao]; \
            const half8 al0 = *(const half8*)&ldsXL[ao]; \
            const half8 ah1 = *(const half8*)&ldsXH[ao + 8192]; \
            const half8 al1 = *(const half8*)&ldsXL[ao + 8192]; \
            acc_hh0 = __builtin_amdgcn_mfma_f32_32x32x16_f16(ah0, BH[s], acc_hh0, 0, 0, 0); \
            acc_hl0 = __builtin_amdgcn_mfma_f32_32x32x16_f16(ah0, BL[s], acc_hl0, 0, 0, 0); \
            acc_hl0 = __builtin_amdgcn_mfma_f32_32x32x16_f16(al0, BH[s], acc_hl0, 0, 0, 0); \
            acc_hh1 = __builtin_amdgcn_mfma_f32_32x32x16_f16(ah1, BH[s], acc_hh1, 0, 0, 0); \
            acc_hl1 = __builtin_amdgcn_mfma_f32_32x32x16_f16(ah1, BL[s], acc_hl1, 0, 0, 0); \
            acc_hl1 = __builtin_amdgcn_mfma_f32_32x32x16_f16(al1, BH[s], acc_hl1, 0, 0, 0); \
        } \
    } while (0)

    LOADB(0, BhA, BlA);
    for (int tile = 0; tile < NTILE; ++tile) {
        #pragma unroll
        for (int q = 0; q < 16; ++q) {
            acc_hh0[q] = 0.f; acc_hl0[q] = 0.f;
            acc_hh1[q] = 0.f; acc_hl1[q] = 0.f;
        }
        const int s0 = tile * 4;
        LOADB(s0 + 1, BhB, BlB);
        MSTEP(0, BhA, BlA);
        LOADB(s0 + 2, BhA, BlA);
        MSTEP(1, BhB, BlB);
        se_reg = wse[tile * 128 + rr];             // L2-hot 32 KB table
        LOADB(s0 + 3, BhB, BlB);
        MSTEP(2, BhA, BlA);
        LOADB(s0 + 4, BhA, BlA);                   // next tile kc=0 (wraps, harmless)
        MSTEP(3, BhB, BlB);
        // ---- tile finalize: dist = fl(fl(s+se) - 2m); ascending code order ----
        const int code = tile * 128 + rr;
        #pragma unroll
        for (int pgi = 0; pgi < 2; ++pgi) {
            #pragma unroll
            for (int q = 0; q < 16; ++q) {
                const float ahh = pgi ? acc_hh1[q] : acc_hh0[q];
                const float ahl = pgi ? acc_hl1[q] : acc_hl0[q];
                const float m = fmaf(ahl, 4.8828125e-4f, ahh) * 0.015625f;
                const float T = s_frag[pgi * 16 + q] + se_reg;
                const float d = fmaf(-2.0f, m, T);
                const int sl = pgi * 16 + q;
                if (d < best_d[sl]) { best_d[sl] = d; best_i[sl] = code; }
            }
        }
    }
#undef LOADB
#undef MSTEP

    // ---- argmin: butterfly over 32 cols (lexicographic), per 32-lane half ----
    #pragma unroll
    for (int off = 1; off < 32; off <<= 1) {
        #pragma unroll
        for (int q = 0; q < 32; ++q) {
            const float d2 = __shfl_xor(best_d[q], off);
            const int   i2 = __shfl_xor(best_i[q], off);
            if (d2 < best_d[q] || (d2 == best_d[q] && i2 < best_i[q])) {
                best_d[q] = d2; best_i[q] = i2;
            }
        }
    }
    if ((lane & 31) == 0) {
        #pragma unroll
        for (int pgi = 0; pgi < 2; ++pgi)
            #pragma unroll
            for (int q = 0; q < 16; ++q) {
                const int p = pgi * 32 + (q & 3) + 8 * (q >> 2) + 4 * hsel;
                ldsFD[w][p] = best_d[pgi * 16 + q];
                ldsFI[w][p] = best_i[pgi * 16 + q];
            }
    }
    __syncthreads();
    if (t < PTB) {
        float bd = ldsFD[0][t];
        int   bi = ldsFI[0][t];
        #pragma unroll
        for (int c2 = 1; c2 < 4; ++c2) {
            const float d2 = ldsFD[c2][t];
            const int   i2 = ldsFI[c2][t];
            if (d2 < bd || (d2 == bd && i2 < bi)) { bd = d2; bi = i2; }
        }
        ldsI[t] = bi;
        out[(size_t)IDX_OFF + n0 + t] = (float)bi;
    }
    __syncthreads();

    // ---- epilogue: gather e row, straight-through out, loss partial ----
    double lsum = 0.0;
    {
        const int p   = t & 63;
        const int cgp = t >> 6;                    // 0..3 (64 channels each)
        const int rowi = ldsI[p];
        const float* erow = emb + (size_t)rowi * DDIM;
        float* ob = out + (size_t)b * CHW + hw0 + p;
        for (int q = 0; q < 64; ++q) {
            const int c = cgp * 64 + q;
            const float e  = erow[c];
            const float xx = xs[(size_t)c * HWSZ + p];
            const float diff = e - xx;             // fl(x_q - xt)
            ob[(size_t)c * HWSZ] = xx + diff;      // straight-through rounding
            lsum += (double)diff * (double)diff;
        }
    }
    #pragma unroll
    for (int off = 32; off > 0; off >>= 1)
        lsum += __shfl_xor(lsum, off);
    if ((t & 63) == 0) ldsL[t >> 6] = lsum;
    __syncthreads();
    if (t == 0) {
        double tot = 0.0;
        #pragma unroll
        for (int wv = 0; wv < 4; ++wv) tot += ldsL[wv];
        atomicAdd(&out[LOSS_OFF], (float)(tot * (1.25 / 4194304.0)));
    }
}

extern "C" void kernel_launch(void* const* d_in, const int* in_sizes, int n_in,
                              void* d_out, int out_size, void* d_ws, size_t ws_size,
                              hipStream_t stream) {
    (void)in_sizes; (void)n_in; (void)out_size; (void)ws_size;
    const float* x   = (const float*)d_in[0];
    const float* emb = (const float*)d_in[1];
    float* out = (float*)d_out;
    unsigned short* ef  = (unsigned short*)d_ws;
    float*          wse = (float*)((char*)d_ws + SE_OFF_B);
    (void)hipMemsetAsync((char*)d_out + (size_t)LOSS_OFF * sizeof(float), 0, sizeof(float), stream);
    prep_frag<<<1024, 256, 0, stream>>>(emb, ef);
    prep_se<<<64, 256, 0, stream>>>(emb, wse);
    vq_kernel<<<NPTS / PTB, 256, 0, stream>>>(x, ef, wse, emb, out);
}